// Round 1
// 550.722 us; speedup vs baseline: 1.0602x; 1.0602x over previous
//
#include <hip/hip_runtime.h>
#include <stdint.h>

typedef unsigned short u16;
typedef __attribute__((ext_vector_type(8))) short short8;
typedef __attribute__((ext_vector_type(4))) float f32x4;

#define B_ 8
#define L_ 2048
#define D_ 1024

// ---------- bf16 helpers (RNE) ----------
__device__ __forceinline__ u16 f2bf(float f) {
    unsigned int u = __float_as_uint(f);
    u = u + 0x7FFFu + ((u >> 16) & 1u);
    return (u16)(u >> 16);
}
__device__ __forceinline__ float bf2f(u16 h) {
    return __uint_as_float(((unsigned int)h) << 16);
}

// ---------- fused fp32->bf16 conversion + zero-row mask, q/k/v in one dispatch ----------
struct CM3 {
    const float* s[3];
    u16* d[3];
    int* m[3];
};
__global__ __launch_bounds__(256) void convmask3_kernel(CM3 c) {
    int sel = blockIdx.y;
    const float* x = c.s[sel];
    u16* xb = c.d[sel];
    int* mask = c.m[sel];
    long row = blockIdx.x;
    int t = threadIdx.x;
    float4 v = ((const float4*)(x + row * D_))[t];
    ushort4 o;
    o.x = f2bf(v.x); o.y = f2bf(v.y); o.z = f2bf(v.z); o.w = f2bf(v.w);
    ((ushort4*)(xb + row * D_))[t] = o;
    float s = v.x + v.y + v.z + v.w;
    #pragma unroll
    for (int off = 32; off; off >>= 1) s += __shfl_down(s, off);
    __shared__ float sh[4];
    if ((t & 63) == 0) sh[t >> 6] = s;
    __syncthreads();
    if (t == 0) {
        float tot = sh[0] + sh[1] + sh[2] + sh[3];
        mask[row] = (tot == 0.0f) ? 1 : 0;
    }
}

// ---------- all 4 weight matrices fp32->bf16 in one dispatch ----------
struct Ptr4 { const float* s0; const float* s1; const float* s2; const float* s3; };
__global__ __launch_bounds__(256) void convert4_kernel(Ptr4 p, u16* __restrict__ dst) {
    const float* srcs[4] = {p.s0, p.s1, p.s2, p.s3};
    const float* src = srcs[blockIdx.y];
    u16* d = dst + (size_t)blockIdx.y * D_ * D_;
    int i = blockIdx.x * 256 + threadIdx.x;
    float4 v = ((const float4*)src)[i];
    ushort4 o;
    o.x = f2bf(v.x); o.y = f2bf(v.y); o.z = f2bf(v.z); o.w = f2bf(v.w);
    ((ushort4*)d)[i] = o;
}

// ---------- block-group skip flags ----------
// blocks: 0..63 q256 | 64..127 k256 | 128..191 v256 | 192..319 kmask128 | 320..831 kmask32
__global__ __launch_bounds__(256) void flags_kernel(const int* __restrict__ mq,
                                                    const int* __restrict__ mk,
                                                    const int* __restrict__ mv,
                                                    int* __restrict__ q256,
                                                    int* __restrict__ k256,
                                                    int* __restrict__ v256,
                                                    int* __restrict__ k128,
                                                    int* __restrict__ k32) {
    int b = blockIdx.x, t = threadIdx.x;
    const int* src; int* dst; int g; int n;
    if (b < 64)       { src = mq; dst = q256; g = b;       n = 256; }
    else if (b < 128) { src = mk; dst = k256; g = b - 64;  n = 256; }
    else if (b < 192) { src = mv; dst = v256; g = b - 128; n = 256; }
    else if (b < 320) { src = mk; dst = k128; g = b - 192; n = 128; }
    else              { src = mk; dst = k32;  g = b - 320; n = 32;  }
    int val = (t < n) ? src[(long)g * n + t] : 1;
    __shared__ int sh;
    if (t == 0) sh = 1;
    __syncthreads();
    if (!val) sh = 0;
    __syncthreads();
    if (t == 0) dst[g] = sh;
}

// ---------- pack kmask32 [B][64] into per-batch uint64 of ACTIVE k-steps ----------
__global__ __launch_bounds__(512) void packbits_kernel(const int* __restrict__ k32,
                                                       unsigned long long* __restrict__ kb) {
    int t = threadIdx.x;
    int b = t >> 6;
    int bit = t & 63;
    unsigned long long m = __ballot(k32[b * 64 + bit] == 0);  // bit set = step active
    if (bit == 0) kb[b] = m;
}

// ---------- async global->LDS 16B ----------
__device__ __forceinline__ void async_cp16(const void* g, void* l) {
    __builtin_amdgcn_global_load_lds((const __attribute__((address_space(1))) unsigned int*)g,
                                     (__attribute__((address_space(3))) unsigned int*)l,
                                     16, 0, 0);
}

// ---------- per-z pointers for the merged projection dispatch (MODE 0) ----------
struct P3 {
    const u16* A[3];
    u16* C[3];
    const float* bias[3];
    const int* rs[3];
};

// ---------- NT bf16 GEMM: C[m,n] = sum_k A[m,k]*B[n,k] (+ epilogue per MODE) ----------
// 256x256 tile, 512 threads = 8 waves (2M x 4N), per-wave 128x64 output (8x4 frags).
// Pipelined: 4-slot LDS ring (4 x 32 KB = 128 KB), prefetch 3 K-tiles ahead with
// counted s_waitcnt vmcnt(8) (never 0 in steady state), ONE raw s_barrier per K-tile,
// s_setprio(1) around each 16-MFMA cluster (T3/T4/T5 from the technique catalog).
// LDS XOR-swizzle kept from the verified kernel: chunk (row,kc) stored at physical
// kc ^ ((row>>1)&3); staging pre-swizzles the GLOBAL source (linear LDS dest as
// required by global_load_lds), fragment reads apply the same involution -> 2-way
// (free) bank aliasing, measured 0 conflicts.
// MODE 0: proj (merged q/k/v via grid.z + P3) : bf16 C = acc + bias[n]
// MODE 1: scores : bf16 C = maskk[n] ? -1e30 : acc*scale
// MODE 2: PV (k-steps gated by kbits bitmask) : bf16 C = acc
// MODE 3: outproj: bf16 C = acc + bias[n] + bf2f(resid[m,n])
#define GBM 256
#define GBN 256
#define GBK 32

// stage one 256x32 A-tile + 256x32 B-tile (32 KB) of K-step `step` into ring slot `slot`
// 4 x global_load_lds(16B) per thread; LDS dest linear in t (wave-uniform base + lane*16)
#define STAGE(step, slot)                                                   \
    do {                                                                    \
        const u16* pa_ = gA + (long)(step) * GBK;                           \
        const u16* pb_ = gB + (long)(step) * GBK;                           \
        u16* la_ = &LDS[(slot)][0] + t * 8;                                 \
        async_cp16(pa_, la_);                                               \
        async_cp16(pa_ + 128 * (long)K, la_ + 4096);                        \
        async_cp16(pb_, la_ + 8192);                                        \
        async_cp16(pb_ + 128 * (long)K, la_ + 12288);                       \
    } while (0)

template <int MODE>
__global__ __launch_bounds__(512, 2) void gemm_nt(const u16* __restrict__ A,
                                                  const u16* __restrict__ Bm,
                                                  void* __restrict__ C,
                                                  const float* __restrict__ bias,
                                                  const u16* __restrict__ resid,
                                                  const int* __restrict__ maskk,
                                                  int N, int K,
                                                  long strideA, long strideB, long strideC,
                                                  float scale,
                                                  const int* __restrict__ rowskip,
                                                  const int* __restrict__ colskip,
                                                  const unsigned long long* __restrict__ kbits,
                                                  int mblocks, int nblocks,
                                                  P3 p3) {
    __shared__ __align__(16) u16 LDS[4][16384];  // 128 KB: slot = A[8192] | B[8192]

    int t = threadIdx.x;
    int lane = t & 63;
    int wave = t >> 6;
    int wr = wave >> 2;  // 0..1 (M half)
    int wc = wave & 3;   // 0..3 (N quarter)
    long m0 = (long)blockIdx.x * GBM;
    long n0 = (long)blockIdx.y * GBN;

    const u16* Ab;
    const u16* Bb;
    char* Cb;
    const float* biasp = bias;
    const int* rs;
    int rsidx;
    if (MODE == 0) {
        int z = blockIdx.z;
        Ab = p3.A[z];
        Bb = Bm + (long)z * D_ * D_;
        Cb = (char*)p3.C[z];
        biasp = p3.bias[z];
        rs = p3.rs[z];
        rsidx = blockIdx.x;
    } else {
        Ab = A + (long)blockIdx.z * strideA;
        Bb = Bm + (long)blockIdx.z * strideB;
        Cb = (char*)C + (long)blockIdx.z * strideC;
        rs = rowskip;
        rsidx = blockIdx.z * mblocks + blockIdx.x;
    }
    const int* mk = (MODE == 1) ? (maskk + (long)blockIdx.z * N) : nullptr;

    bool skipK = false;
    if (rs && rs[rsidx]) skipK = true;
    if (MODE == 1 && colskip && colskip[blockIdx.z * nblocks + blockIdx.y]) skipK = true;

    f32x4 acc[8][4] = {};

    // staging: thread t covers LDS chunks t and t+512 of each of A/B.
    // linear chunk p -> (row = p>>2, phys kc = p&3) holding logical kc = (p&3)^((p>>3)&3)
    int srow = t >> 2;                                  // 0..127 (+128 on 2nd issue)
    int kc = ((t & 3) ^ ((t >> 3) & 3)) * 8;            // pre-swizzled global k-offset
    const u16* gA = Ab + (m0 + srow) * (long)K + kc;
    const u16* gB = Bb + (n0 + srow) * (long)K + kc;

    // fragment-read swizzled k-chunk (invariant across frag idx: 16i>>1 = 0 mod 4)
    int sw = ((lane >> 4) ^ ((lane >> 1) & 3)) * 8;
    int arow0 = wr * 128 + (lane & 15);
    int brow0 = wc * 64 + (lane & 15);

    if (!skipK) {
        unsigned long long bs = 0;
        int NT;
        if (MODE == 2) {
            bs = kbits[blockIdx.z];
            NT = __popcll(bs);
        } else {
            NT = K / GBK;
        }

        // prologue: stage K-tiles 0..2 into slots 0..2 (12 loads/thread max in flight)
        int npro = NT < 3 ? NT : 3;
        for (int i = 0; i < npro; i++) {
            int st = i;
            if (MODE == 2) { st = __builtin_ctzll(bs); bs &= bs - 1; }
            STAGE(st, i);
        }
        int nstaged = npro;

        for (int tt = 0; tt < NT; tt++) {
            // wait for tile tt's 4 loads only: allow {tt+1, tt+2} (8 loads) in flight.
            int rem = NT - 1 - tt;
            if (rem > 1)      asm volatile("s_waitcnt vmcnt(8)" ::: "memory");
            else if (rem == 1) asm volatile("s_waitcnt vmcnt(4)" ::: "memory");
            else               asm volatile("s_waitcnt vmcnt(0)" ::: "memory");
            __builtin_amdgcn_s_barrier();   // all waves: tile tt present, slot (tt-1)&3 free
            asm volatile("" ::: "memory");

            if (nstaged < NT) {             // prefetch tile tt+3 into the freed slot
                int st = nstaged;
                if (MODE == 2) { st = __builtin_ctzll(bs); bs &= bs - 1; }
                STAGE(st, nstaged & 3);
                nstaged++;
            }

            const u16* As_ = &LDS[tt & 3][0];
            const u16* Bs_ = As_ + 8192;
            short8 bfr[4], af[4];
            #pragma unroll
            for (int j = 0; j < 4; j++)
                bfr[j] = *(const short8*)&Bs_[(brow0 + j * 16) * GBK + sw];
            #pragma unroll
            for (int i = 0; i < 4; i++)
                af[i] = *(const short8*)&As_[(arow0 + i * 16) * GBK + sw];
            __builtin_amdgcn_s_setprio(1);
            #pragma unroll
            for (int i = 0; i < 4; i++)
                #pragma unroll
                for (int j = 0; j < 4; j++)
                    acc[i][j] = __builtin_amdgcn_mfma_f32_16x16x32_bf16(af[i], bfr[j],
                                                                        acc[i][j], 0, 0, 0);
            __builtin_amdgcn_s_setprio(0);
            #pragma unroll
            for (int i = 0; i < 4; i++)
                af[i] = *(const short8*)&As_[(arow0 + 64 + i * 16) * GBK + sw];
            __builtin_amdgcn_s_setprio(1);
            #pragma unroll
            for (int i = 0; i < 4; i++)
                #pragma unroll
                for (int j = 0; j < 4; j++)
                    acc[4 + i][j] = __builtin_amdgcn_mfma_f32_16x16x32_bf16(af[i], bfr[j],
                                                                            acc[4 + i][j], 0, 0, 0);
            __builtin_amdgcn_s_setprio(0);
        }
    }

    long crow0 = m0 + wr * 128;
    long ccol0 = n0 + wc * 64;
    #pragma unroll
    for (int i = 0; i < 8; i++) {
        #pragma unroll
        for (int j = 0; j < 4; j++) {
            long row = crow0 + i * 16 + (lane >> 4) * 4;
            long col = ccol0 + j * 16 + (lane & 15);
            #pragma unroll
            for (int r = 0; r < 4; r++) {
                float vv = acc[i][j][r];
                long rr = row + r;
                if (MODE == 0) {
                    ((u16*)Cb)[rr * N + col] = f2bf(vv + biasp[col]);
                } else if (MODE == 1) {
                    float s = mk[col] ? -1e30f : vv * scale;
                    ((u16*)Cb)[rr * N + col] = f2bf(s);
                } else if (MODE == 2) {
                    ((u16*)Cb)[rr * N + col] = f2bf(vv);
                } else {
                    float x = vv + biasp[col] + bf2f(resid[rr * (long)N + col]);
                    ((u16*)Cb)[rr * N + col] = f2bf(x);
                }
            }
        }
    }
}

// ---------- row softmax over Lk=2048 bf16 scores, query-mask folded in ----------
__global__ __launch_bounds__(256) void softmax_kernel(const u16* __restrict__ S,
                                                      u16* __restrict__ P,
                                                      const int* __restrict__ maskq) {
    long row = blockIdx.x;
    int t = threadIdx.x;
    const u16* Sr = S + row * L_;
    u16* Pr = P + row * L_;

    if (maskq[row]) {
        short8 z = {};
        *(short8*)&Pr[t * 8] = z;
        return;
    }

    short8 raw = *(const short8*)&Sr[t * 8];
    float s[8];
    #pragma unroll
    for (int e = 0; e < 8; e++) s[e] = bf2f((u16)raw[e]);

    float mx = s[0];
    #pragma unroll
    for (int e = 1; e < 8; e++) mx = fmaxf(mx, s[e]);
    #pragma unroll
    for (int off = 32; off; off >>= 1) mx = fmaxf(mx, __shfl_down(mx, off));
    __shared__ float sh[4];
    if ((t & 63) == 0) sh[t >> 6] = mx;
    __syncthreads();
    mx = fmaxf(fmaxf(sh[0], sh[1]), fmaxf(sh[2], sh[3]));
    __syncthreads();

    float e8[8], sum = 0.f;
    #pragma unroll
    for (int e = 0; e < 8; e++) { e8[e] = __expf(s[e] - mx); sum += e8[e]; }
    #pragma unroll
    for (int off = 32; off; off >>= 1) sum += __shfl_down(sum, off);
    if ((t & 63) == 0) sh[t >> 6] = sum;
    __syncthreads();
    sum = sh[0] + sh[1] + sh[2] + sh[3];
    float inv = 1.0f / sum;

    short8 o;
    #pragma unroll
    for (int e = 0; e < 8; e++) o[e] = (short)f2bf(e8[e] * inv);
    *(short8*)&Pr[t * 8] = o;
}

// ---------- bf16 transpose per batch: dst[b][d][key] = src[b][key][d] ----------
__global__ __launch_bounds__(256) void transpose_k(const u16* __restrict__ src,
                                                   u16* __restrict__ dst) {
    __shared__ u16 tile[32][34];
    long b = blockIdx.z;
    const u16* s = src + b * (long)L_ * D_;
    u16* d = dst + b * (long)L_ * D_;
    int gx = blockIdx.x * 32;  // d
    int gy = blockIdx.y * 32;  // key
    int tx = threadIdx.x, ty = threadIdx.y;
    #pragma unroll
    for (int r = 0; r < 32; r += 8)
        tile[ty + r][tx] = s[(long)(gy + ty + r) * D_ + gx + tx];
    __syncthreads();
    #pragma unroll
    for (int r = 0; r < 32; r += 8)
        d[(long)(gx + ty + r) * L_ + gy + tx] = tile[tx][ty + r];
}

// ---------- LayerNorm (no affine), eps=1e-5; bf16 input, f32 output ----------
__global__ __launch_bounds__(256) void layernorm_kernel(const u16* __restrict__ X,
                                                        float* __restrict__ O) {
    long row = blockIdx.x;
    int t = threadIdx.x;
    ushort4 u = ((const ushort4*)(X + row * D_))[t];
    float x0 = bf2f(u.x), x1 = bf2f(u.y), x2 = bf2f(u.z), x3 = bf2f(u.w);
    float s = x0 + x1 + x2 + x3;
    #pragma unroll
    for (int off = 32; off; off >>= 1) s += __shfl_down(s, off);
    __shared__ float sh[4];
    if ((t & 63) == 0) sh[t >> 6] = s;
    __syncthreads();
    float mu = (sh[0] + sh[1] + sh[2] + sh[3]) * (1.0f / D_);
    __syncthreads();

    float d0 = x0 - mu, d1 = x1 - mu, d2 = x2 - mu, d3 = x3 - mu;
    float ss = d0 * d0 + d1 * d1 + d2 * d2 + d3 * d3;
    #pragma unroll
    for (int off = 32; off; off >>= 1) ss += __shfl_down(ss, off);
    if ((t & 63) == 0) sh[t >> 6] = ss;
    __syncthreads();
    float var = (sh[0] + sh[1] + sh[2] + sh[3]) * (1.0f / D_);
    float rs = rsqrtf(var + 1e-5f);

    float4 o;
    o.x = d0 * rs; o.y = d1 * rs; o.z = d2 * rs; o.w = d3 * rs;
    ((float4*)(O + row * D_))[t] = o;
}

extern "C" void kernel_launch(void* const* d_in, const int* in_sizes, int n_in,
                              void* d_out, int out_size, void* d_ws, size_t ws_size,
                              hipStream_t stream) {
    const float* q  = (const float*)d_in[0];
    const float* k  = (const float*)d_in[1];
    const float* v  = (const float*)d_in[2];
    const float* Wq = (const float*)d_in[3];
    const float* bq = (const float*)d_in[4];
    const float* Wk = (const float*)d_in[5];
    const float* bk = (const float*)d_in[6];
    const float* Wv = (const float*)d_in[7];
    const float* bv = (const float*)d_in[8];
    const float* Wo = (const float*)d_in[9];
    const float* bo = (const float*)d_in[10];
    float* out = (float*)d_out;

    char* ws = (char*)d_ws;
    const size_t SZ = (size_t)B_ * L_ * D_ * 2;  // 33,554,432 B (one [B,L,D] bf16)

    // Region A (4*SZ): qb,kb,vb,vpb -> then S(2*SZ) | P at +2*SZ -> then O(SZ) | X at +2*SZ
    u16* qb   = (u16*)(ws + 0 * SZ);
    u16* kb   = (u16*)(ws + 1 * SZ);
    u16* vb   = (u16*)(ws + 2 * SZ);
    u16* vpb  = (u16*)(ws + 3 * SZ);
    u16* Sbuf = (u16*)(ws + 0 * SZ);       // 2*SZ bytes, alive: scores GEMM -> softmax
    u16* Pbuf = (u16*)(ws + 2 * SZ);       // 2*SZ bytes, alive: softmax -> PV GEMM
    u16* Obuf = (u16*)(ws + 0 * SZ);       // SZ bytes,  alive: PV GEMM -> outproj
    u16* Xbuf = (u16*)(ws + 2 * SZ);       // SZ bytes,  alive: outproj -> layernorm
    char* p = ws + 4 * SZ;
    u16* qpb = (u16*)p; p += SZ;           // projected q (bf16), also residual
    u16* kpb = (u16*)p; p += SZ;
    u16* vpT = (u16*)p; p += SZ;           // transposed projected v
    u16* Wqb = (u16*)p; p += (size_t)D_ * D_ * 2;  // Wqb..Wob contiguous
    u16* Wkb = (u16*)p; p += (size_t)D_ * D_ * 2;
    u16* Wvb = (u16*)p; p += (size_t)D_ * D_ * 2;
    u16* Wob = (u16*)p; p += (size_t)D_ * D_ * 2;
    int* maskq = (int*)p; p += (size_t)B_ * L_ * 4;
    int* maskk = (int*)p; p += (size_t)B_ * L_ * 4;
    int* maskv = (int*)p; p += (size_t)B_ * L_ * 4;
    int* q256 = (int*)p; p += 64 * 4;        // [B*L/256]
    int* k256 = (int*)p; p += 64 * 4;
    int* v256 = (int*)p; p += 64 * 4;
    int* kmask128 = (int*)p; p += 128 * 4;   // [B][L/128]
    int* kmask32  = (int*)p; p += 512 * 4;   // [B][L/32]
    unsigned long long* kbits = (unsigned long long*)p; p += 8 * 8;  // [B] active-step bitmask

    P3 noP3 = {};

    // 1. fused conversions + masks (q,k,v in one dispatch), weights, flags, bitmask
    CM3 cm;
    cm.s[0] = q;  cm.s[1] = k;  cm.s[2] = v;
    cm.d[0] = qb; cm.d[1] = kb; cm.d[2] = vb;
    cm.m[0] = maskq; cm.m[1] = maskk; cm.m[2] = maskv;
    convmask3_kernel<<<dim3(B_ * L_, 3), 256, 0, stream>>>(cm);
    Ptr4 wp{Wq, Wk, Wv, Wo};
    convert4_kernel<<<dim3(D_ * D_ / 4 / 256, 4), 256, 0, stream>>>(wp, Wqb);
    flags_kernel<<<832, 256, 0, stream>>>(maskq, maskk, maskv, q256, k256, v256, kmask128, kmask32);
    packbits_kernel<<<1, 512, 0, stream>>>(kmask32, kbits);

    // 2. merged projections: 3 x [16384,1024] x [1024,1024]^T via grid.z
    P3 pj;
    pj.A[0] = qb;  pj.A[1] = kb;  pj.A[2] = vb;
    pj.C[0] = qpb; pj.C[1] = kpb; pj.C[2] = vpb;
    pj.bias[0] = bq; pj.bias[1] = bk; pj.bias[2] = bv;
    pj.rs[0] = q256; pj.rs[1] = k256; pj.rs[2] = v256;
    gemm_nt<0><<<dim3(B_ * L_ / GBM, D_ / GBN, 3), 512, 0, stream>>>(
        nullptr, Wqb, nullptr, nullptr, nullptr, nullptr, D_, D_, 0, 0, 0, 0.f,
        nullptr, nullptr, nullptr, 0, 4, pj);

    // 3. transpose vp for the PV GEMM
    transpose_k<<<dim3(D_ / 32, L_ / 32, B_), dim3(32, 8), 0, stream>>>(vpb, vpT);

    // 4. scores: S[b,i,j] = scale * qp_i . kp_j, key-masked; skip q-/k-masked blocks
    gemm_nt<1><<<dim3(L_ / GBM, L_ / GBN, B_), 512, 0, stream>>>(
        qpb, kpb, Sbuf, nullptr, nullptr, maskk, L_, D_,
        (long)L_ * D_, (long)L_ * D_, (long)L_ * L_ * 2, 0.03125f,
        q256, k256, nullptr, L_ / GBM, L_ / GBN, noP3);

    // 5. softmax rows (query-mask folded into P)
    softmax_kernel<<<B_ * L_, 256, 0, stream>>>(Sbuf, Pbuf, maskq);

    // 6. O = P @ vp (via vpT, NT); skip q-masked row blocks; k-steps gated by kbits
    gemm_nt<2><<<dim3(L_ / GBM, D_ / GBN, B_), 512, 0, stream>>>(
        Pbuf, vpT, Obuf, nullptr, nullptr, nullptr, D_, L_,
        (long)L_ * L_, (long)D_ * L_, (long)L_ * D_ * 2, 0.f,
        q256, nullptr, kbits, L_ / GBM, D_ / GBN, noP3);

    // 7. out-proj + bias + residual(qp) -> bf16; skip q-masked row blocks (acc=0 exact)
    gemm_nt<3><<<dim3(B_ * L_ / GBM, D_ / GBN, 1), 512, 0, stream>>>(
        Obuf, Wob, Xbuf, bo, qpb, nullptr, D_, D_, 0, 0, 0, 0.f,
        q256, nullptr, nullptr, B_ * L_ / GBM, D_ / GBN, noP3);

    // 8. LayerNorm (bf16 in, f32 out) -> d_out
    layernorm_kernel<<<B_ * L_, 256, 0, stream>>>(Xbuf, out);
}

// Round 2
// 550.367 us; speedup vs baseline: 1.0609x; 1.0006x over previous
//
#include <hip/hip_runtime.h>
#include <stdint.h>

typedef unsigned short u16;
typedef __attribute__((ext_vector_type(8))) short short8;
typedef __attribute__((ext_vector_type(4))) float f32x4;

#define B_ 8
#define L_ 2048
#define D_ 1024

// ---------- bf16 helpers (RNE) ----------
__device__ __forceinline__ u16 f2bf(float f) {
    unsigned int u = __float_as_uint(f);
    u = u + 0x7FFFu + ((u >> 16) & 1u);
    return (u16)(u >> 16);
}
__device__ __forceinline__ float bf2f(u16 h) {
    return __uint_as_float(((unsigned int)h) << 16);
}

// ---------- fused fp32->bf16 conversion + zero-row mask, q/k/v in one dispatch ----------
struct CM3 {
    const float* s[3];
    u16* d[3];
    int* m[3];
};
__global__ __launch_bounds__(256) void convmask3_kernel(CM3 c) {
    int sel = blockIdx.y;
    const float* x = c.s[sel];
    u16* xb = c.d[sel];
    int* mask = c.m[sel];
    long row = blockIdx.x;
    int t = threadIdx.x;
    float4 v = ((const float4*)(x + row * D_))[t];
    ushort4 o;
    o.x = f2bf(v.x); o.y = f2bf(v.y); o.z = f2bf(v.z); o.w = f2bf(v.w);
    ((ushort4*)(xb + row * D_))[t] = o;
    float s = v.x + v.y + v.z + v.w;
    #pragma unroll
    for (int off = 32; off; off >>= 1) s += __shfl_down(s, off);
    __shared__ float sh[4];
    if ((t & 63) == 0) sh[t >> 6] = s;
    __syncthreads();
    if (t == 0) {
        float tot = sh[0] + sh[1] + sh[2] + sh[3];
        mask[row] = (tot == 0.0f) ? 1 : 0;
    }
}

// ---------- all 4 weight matrices fp32->bf16 in one dispatch ----------
struct Ptr4 { const float* s0; const float* s1; const float* s2; const float* s3; };
__global__ __launch_bounds__(256) void convert4_kernel(Ptr4 p, u16* __restrict__ dst) {
    const float* srcs[4] = {p.s0, p.s1, p.s2, p.s3};
    const float* src = srcs[blockIdx.y];
    u16* d = dst + (size_t)blockIdx.y * D_ * D_;
    int i = blockIdx.x * 256 + threadIdx.x;
    float4 v = ((const float4*)src)[i];
    ushort4 o;
    o.x = f2bf(v.x); o.y = f2bf(v.y); o.z = f2bf(v.z); o.w = f2bf(v.w);
    ((ushort4*)d)[i] = o;
}

// ---------- block-group skip flags ----------
// blocks: 0..63 q256 | 64..127 k256 | 128..191 v256 | 192..319 kmask128 | 320..831 kmask32
__global__ __launch_bounds__(256) void flags_kernel(const int* __restrict__ mq,
                                                    const int* __restrict__ mk,
                                                    const int* __restrict__ mv,
                                                    int* __restrict__ q256,
                                                    int* __restrict__ k256,
                                                    int* __restrict__ v256,
                                                    int* __restrict__ k128,
                                                    int* __restrict__ k32) {
    int b = blockIdx.x, t = threadIdx.x;
    const int* src; int* dst; int g; int n;
    if (b < 64)       { src = mq; dst = q256; g = b;       n = 256; }
    else if (b < 128) { src = mk; dst = k256; g = b - 64;  n = 256; }
    else if (b < 192) { src = mv; dst = v256; g = b - 128; n = 256; }
    else if (b < 320) { src = mk; dst = k128; g = b - 192; n = 128; }
    else              { src = mk; dst = k32;  g = b - 320; n = 32;  }
    int val = (t < n) ? src[(long)g * n + t] : 1;
    __shared__ int sh;
    if (t == 0) sh = 1;
    __syncthreads();
    if (!val) sh = 0;
    __syncthreads();
    if (t == 0) dst[g] = sh;
}

// ---------- pack kmask32 [B][64] into per-batch 32-bit mask of ACTIVE 64-row k-steps ----------
// (BK=64 now: step i active iff either 32-row half is active)
__global__ __launch_bounds__(256) void packbits_kernel(const int* __restrict__ k32,
                                                       unsigned long long* __restrict__ kb) {
    int t = threadIdx.x;            // 256 threads: b = t>>5, i = t&31
    int b = t >> 5;
    int i = t & 31;
    bool act = (k32[b * 64 + 2 * i] == 0) || (k32[b * 64 + 2 * i + 1] == 0);
    unsigned long long m = __ballot(act);   // wave covers batches (b, b+1)
    if (i == 0) kb[b] = (b & 1) ? (m >> 32) : (m & 0xffffffffULL);
}

// ---------- async global->LDS 16B ----------
__device__ __forceinline__ void async_cp16(const void* g, void* l) {
    __builtin_amdgcn_global_load_lds((const __attribute__((address_space(1))) unsigned int*)g,
                                     (__attribute__((address_space(3))) unsigned int*)l,
                                     16, 0, 0);
}

// ---------- per-z pointers for the merged projection dispatch (MODE 0) ----------
struct P3 {
    const u16* A[3];
    u16* C[3];
    const float* bias[3];
    const int* rs[3];
};

// ---------- NT bf16 GEMM: C[m,n] = sum_k A[m,k]*B[n,k] (+ epilogue per MODE) ----------
// 256x256 tile, 512 threads = 8 waves (2M x 4N), per-wave 128x64 output.
// 8-phase schedule (m201 template): per BK=64 K-tile, 4 quadrant phases of exactly
// 16 MFMA each: {ds_read frags || stage freed half-tile -> barrier -> lgkmcnt(0) ->
// setprio(1) MFMA setprio(0) -> barrier}. LDS = 2 buffers x 4 halves {A0,A1,B0,B1}
// (128x64 bf16 = 16KB each, 128KB total). Quadrant order (0,0),(0,1),(1,1),(1,0)
// frees A0 after ph1, B1 after ph2, A1/B0 after ph3; stages: ph0 -> A1,B0(t+1) into
// other buf; ph2 -> A0(t+2), ph3 -> B1(t+2) into current buf. ONE counted
// s_waitcnt vmcnt(4) per K-tile (ph3) confirms the whole next tile (4-6 phase lead,
// never drains to 0 until the tail). 3-bit XOR chunk swizzle (phys = chunk^(row&7))
// applied via pre-swizzled global source (linear LDS dest, rule 21) keeps
// ds_read_b128 conflict-free.
// MODE 0: proj (merged q/k/v via grid.z + P3) : bf16 C = acc + bias[n]
// MODE 1: scores : bf16 C = maskk[n] ? -1e30 : acc*scale
// MODE 2: PV (64-row k-steps gated by kbits) : bf16 C = acc
// MODE 3: outproj: bf16 C = acc + bias[n] + bf2f(resid[m,n])
#define GBM 256
#define GBN 256
#define GBK 64

// stage one 128x64 half-tile of K-step STEP into LDS[BUF][HALF]; 2 x 16B per thread.
// HALF: 0=A rows 0-127, 1=A rows 128-255, 2=B rows 0-127, 3=B rows 128-255.
#define STG(BUF, HALF, STEP)                                                     \
    do {                                                                         \
        const u16* g_ = (((HALF) < 2) ? gA0 : gB0) +                             \
                        (long)((HALF) & 1) * 128 * (long)K + (long)(STEP) * GBK; \
        u16* l_ = &LDS[BUF][HALF][t * 8];                                        \
        async_cp16(g_, l_);                                                      \
        async_cp16(g_ + 64 * (long)K, l_ + 4096);                                \
    } while (0)

#define DSA(QM)                                                                  \
    _Pragma("unroll")                                                            \
    for (int i_ = 0; i_ < 4; i_++) {                                             \
        af[i_][0] = *(const short8*)&LDS[buf][QM][aoff + i_ * 1024 + c0];        \
        af[i_][1] = *(const short8*)&LDS[buf][QM][aoff + i_ * 1024 + c1];        \
    }
#define DSB(QN)                                                                  \
    _Pragma("unroll")                                                            \
    for (int j_ = 0; j_ < 2; j_++) {                                             \
        bf[j_][0] = *(const short8*)&LDS[buf][2 + (QN)][boff + j_ * 1024 + c0];  \
        bf[j_][1] = *(const short8*)&LDS[buf][2 + (QN)][boff + j_ * 1024 + c1];  \
    }
#define MF(QM, QN)                                                               \
    __builtin_amdgcn_s_setprio(1);                                               \
    _Pragma("unroll")                                                            \
    for (int i_ = 0; i_ < 4; i_++) {                                             \
        _Pragma("unroll")                                                        \
        for (int j_ = 0; j_ < 2; j_++) {                                         \
            acc[QM][QN][i_][j_] = __builtin_amdgcn_mfma_f32_16x16x32_bf16(       \
                af[i_][0], bf[j_][0], acc[QM][QN][i_][j_], 0, 0, 0);             \
            acc[QM][QN][i_][j_] = __builtin_amdgcn_mfma_f32_16x16x32_bf16(       \
                af[i_][1], bf[j_][1], acc[QM][QN][i_][j_], 0, 0, 0);             \
        }                                                                        \
    }                                                                            \
    __builtin_amdgcn_s_setprio(0);

#define BAR_IN                                                  \
    do {                                                        \
        asm volatile("" ::: "memory");                          \
        __builtin_amdgcn_s_barrier();                           \
        asm volatile("s_waitcnt lgkmcnt(0)" ::: "memory");      \
        __builtin_amdgcn_sched_barrier(0);                      \
    } while (0)
#define BAR_OUT                                                 \
    do {                                                        \
        asm volatile("" ::: "memory");                          \
        __builtin_amdgcn_s_barrier();                           \
    } while (0)

template <int MODE>
__global__ __launch_bounds__(512, 2) void gemm_nt(const u16* __restrict__ A,
                                                  const u16* __restrict__ Bm,
                                                  void* __restrict__ C,
                                                  const float* __restrict__ bias,
                                                  const u16* __restrict__ resid,
                                                  const int* __restrict__ maskk,
                                                  int N, int K,
                                                  long strideA, long strideB, long strideC,
                                                  float scale,
                                                  const int* __restrict__ rowskip,
                                                  const int* __restrict__ colskip,
                                                  const unsigned long long* __restrict__ kbits,
                                                  int mblocks, int nblocks,
                                                  P3 p3) {
    __shared__ __align__(16) u16 LDS[2][4][8192];  // 128 KB: buf x {A0,A1,B0,B1} x 128x64

    int t = threadIdx.x;
    int lane = t & 63;
    int wave = t >> 6;
    int wr2 = wave >> 2;  // 0..1 (M half)
    int wc4 = wave & 3;   // 0..3 (N quarter)
    long m0 = (long)blockIdx.x * GBM;
    long n0 = (long)blockIdx.y * GBN;

    const u16* Ab;
    const u16* Bb;
    char* Cb;
    const float* biasp = bias;
    const int* rs;
    int rsidx;
    if (MODE == 0) {
        int z = blockIdx.z;
        Ab = p3.A[z];
        Bb = Bm + (long)z * D_ * D_;
        Cb = (char*)p3.C[z];
        biasp = p3.bias[z];
        rs = p3.rs[z];
        rsidx = blockIdx.x;
    } else {
        Ab = A + (long)blockIdx.z * strideA;
        Bb = Bm + (long)blockIdx.z * strideB;
        Cb = (char*)C + (long)blockIdx.z * strideC;
        rs = rowskip;
        rsidx = blockIdx.z * mblocks + blockIdx.x;
    }
    const int* mk = (MODE == 1) ? (maskk + (long)blockIdx.z * N) : nullptr;

    bool skipK = false;
    if (rs && rs[rsidx]) skipK = true;
    if (MODE == 1 && colskip && colskip[blockIdx.z * nblocks + blockIdx.y]) skipK = true;

    f32x4 acc[2][2][4][2] = {};

    // staging address: thread t covers linear 16B-chunks t (row t>>3) and t+512 (row +64)
    // of each half-tile; pre-swizzled global k-offset so LDS stays linear (rule 21).
    int kcx = ((t & 7) ^ ((t >> 3) & 7)) * 8;
    const u16* gA0 = Ab + (m0 + (t >> 3)) * (long)K + kcx;
    const u16* gB0 = Bb + (n0 + (t >> 3)) * (long)K + kcx;

    // fragment-read offsets (elems) within a half; swizzled chunk for ksteps 0/1
    int aoff = (wr2 * 64 + (lane & 15)) * 64;
    int boff = (wc4 * 32 + (lane & 15)) * 64;
    int c0 = ((lane >> 4) ^ (lane & 7)) * 8;
    int c1 = ((4 + (lane >> 4)) ^ (lane & 7)) * 8;

    if (!skipK) {
        unsigned long long bs = 0;
        int NT;
        if (MODE == 2) {
            bs = kbits[blockIdx.z];
            NT = __popcll(bs);
        } else {
            NT = K / GBK;
        }

        if (NT > 0) {
            int st0, st1 = 0, st2 = 0;
            if (MODE == 2) { st0 = __builtin_ctzll(bs); bs &= bs - 1; } else st0 = 0;

            // prologue queue: [A0(0), B1(0), A1(0), B0(0), A0(1), B1(1)]
            STG(0, 0, st0);
            STG(0, 3, st0);
            STG(0, 1, st0);
            STG(0, 2, st0);
            if (NT >= 2) {
                if (MODE == 2) { st1 = __builtin_ctzll(bs); bs &= bs - 1; } else st1 = 1;
                STG(1, 0, st1);
                STG(1, 3, st1);
                asm volatile("s_waitcnt vmcnt(4)" ::: "memory");
            } else {
                asm volatile("s_waitcnt vmcnt(0)" ::: "memory");
            }
            asm volatile("" ::: "memory");
            __builtin_amdgcn_s_barrier();

            if (NT >= 3) {
                if (MODE == 2) { st2 = __builtin_ctzll(bs); bs &= bs - 1; } else st2 = 2;
            }

            for (int tt = 0; tt < NT; tt++) {
                int buf = tt & 1;
                int bufN = buf ^ 1;
                bool s0 = (tt + 1 < NT);
                bool s2 = (tt + 2 < NT);
                short8 af[4][2], bf[2][2];

                // ---- ph0: quadrant (0,0); stage A1,B0 of tile tt+1 into other buf
                DSA(0); DSB(0);
                if (s0) { STG(bufN, 1, st1); STG(bufN, 2, st1); }
                asm volatile("s_waitcnt lgkmcnt(8)" ::: "memory");
                BAR_IN; MF(0, 0); BAR_OUT;

                // ---- ph1: quadrant (0,1); A0 reused in regs, read B1
                DSB(1);
                BAR_IN; MF(0, 1); BAR_OUT;

                // ---- ph2: quadrant (1,1); read A1 (B1 reused); stage A0(tt+2)
                DSA(1);
                if (s2) STG(buf, 0, st2);
                BAR_IN; MF(1, 1); BAR_OUT;

                // ---- ph3: quadrant (1,0); re-read B0 (A1 reused); stage B1(tt+2);
                //      single counted vmcnt confirms all of tile tt+1.
                DSB(0);
                if (s2) {
                    STG(buf, 3, st2);
                    asm volatile("s_waitcnt vmcnt(4)" ::: "memory");
                } else if (s0) {
                    asm volatile("s_waitcnt vmcnt(0)" ::: "memory");
                }
                BAR_IN; MF(1, 0); BAR_OUT;

                st1 = st2;
                if (MODE == 2) {
                    if (tt + 3 < NT) { st2 = __builtin_ctzll(bs); bs &= bs - 1; }
                } else {
                    st2 = tt + 3;
                }
            }
        }
    }

    // ---- epilogue: C write ----
    #pragma unroll
    for (int QM = 0; QM < 2; QM++) {
        #pragma unroll
        for (int QN = 0; QN < 2; QN++) {
            #pragma unroll
            for (int i = 0; i < 4; i++) {
                #pragma unroll
                for (int j = 0; j < 2; j++) {
                    long row = m0 + QM * 128 + wr2 * 64 + i * 16 + (lane >> 4) * 4;
                    long col = n0 + QN * 128 + wc4 * 32 + j * 16 + (lane & 15);
                    #pragma unroll
                    for (int r = 0; r < 4; r++) {
                        float vv = acc[QM][QN][i][j][r];
                        long rr = row + r;
                        if (MODE == 0) {
                            ((u16*)Cb)[rr * N + col] = f2bf(vv + biasp[col]);
                        } else if (MODE == 1) {
                            float s = mk[col] ? -1e30f : vv * scale;
                            ((u16*)Cb)[rr * N + col] = f2bf(s);
                        } else if (MODE == 2) {
                            ((u16*)Cb)[rr * N + col] = f2bf(vv);
                        } else {
                            float x = vv + biasp[col] + bf2f(resid[rr * (long)N + col]);
                            ((u16*)Cb)[rr * N + col] = f2bf(x);
                        }
                    }
                }
            }
        }
    }
}

// ---------- row softmax over Lk=2048 bf16 scores, query-mask folded in ----------
__global__ __launch_bounds__(256) void softmax_kernel(const u16* __restrict__ S,
                                                      u16* __restrict__ P,
                                                      const int* __restrict__ maskq) {
    long row = blockIdx.x;
    int t = threadIdx.x;
    const u16* Sr = S + row * L_;
    u16* Pr = P + row * L_;

    if (maskq[row]) {
        short8 z = {};
        *(short8*)&Pr[t * 8] = z;
        return;
    }

    short8 raw = *(const short8*)&Sr[t * 8];
    float s[8];
    #pragma unroll
    for (int e = 0; e < 8; e++) s[e] = bf2f((u16)raw[e]);

    float mx = s[0];
    #pragma unroll
    for (int e = 1; e < 8; e++) mx = fmaxf(mx, s[e]);
    #pragma unroll
    for (int off = 32; off; off >>= 1) mx = fmaxf(mx, __shfl_down(mx, off));
    __shared__ float sh[4];
    if ((t & 63) == 0) sh[t >> 6] = mx;
    __syncthreads();
    mx = fmaxf(fmaxf(sh[0], sh[1]), fmaxf(sh[2], sh[3]));
    __syncthreads();

    float e8[8], sum = 0.f;
    #pragma unroll
    for (int e = 0; e < 8; e++) { e8[e] = __expf(s[e] - mx); sum += e8[e]; }
    #pragma unroll
    for (int off = 32; off; off >>= 1) sum += __shfl_down(sum, off);
    if ((t & 63) == 0) sh[t >> 6] = sum;
    __syncthreads();
    sum = sh[0] + sh[1] + sh[2] + sh[3];
    float inv = 1.0f / sum;

    short8 o;
    #pragma unroll
    for (int e = 0; e < 8; e++) o[e] = (short)f2bf(e8[e] * inv);
    *(short8*)&Pr[t * 8] = o;
}

// ---------- bf16 transpose per batch: dst[b][d][key] = src[b][key][d] ----------
__global__ __launch_bounds__(256) void transpose_k(const u16* __restrict__ src,
                                                   u16* __restrict__ dst) {
    __shared__ u16 tile[32][34];
    long b = blockIdx.z;
    const u16* s = src + b * (long)L_ * D_;
    u16* d = dst + b * (long)L_ * D_;
    int gx = blockIdx.x * 32;  // d
    int gy = blockIdx.y * 32;  // key
    int tx = threadIdx.x, ty = threadIdx.y;
    #pragma unroll
    for (int r = 0; r < 32; r += 8)
        tile[ty + r][tx] = s[(long)(gy + ty + r) * D_ + gx + tx];
    __syncthreads();
    #pragma unroll
    for (int r = 0; r < 32; r += 8)
        d[(long)(gx + ty + r) * L_ + gy + tx] = tile[tx][ty + r];
}

// ---------- LayerNorm (no affine), eps=1e-5; bf16 input, f32 output ----------
__global__ __launch_bounds__(256) void layernorm_kernel(const u16* __restrict__ X,
                                                        float* __restrict__ O) {
    long row = blockIdx.x;
    int t = threadIdx.x;
    ushort4 u = ((const ushort4*)(X + row * D_))[t];
    float x0 = bf2f(u.x), x1 = bf2f(u.y), x2 = bf2f(u.z), x3 = bf2f(u.w);
    float s = x0 + x1 + x2 + x3;
    #pragma unroll
    for (int off = 32; off; off >>= 1) s += __shfl_down(s, off);
    __shared__ float sh[4];
    if ((t & 63) == 0) sh[t >> 6] = s;
    __syncthreads();
    float mu = (sh[0] + sh[1] + sh[2] + sh[3]) * (1.0f / D_);
    __syncthreads();

    float d0 = x0 - mu, d1 = x1 - mu, d2 = x2 - mu, d3 = x3 - mu;
    float ss = d0 * d0 + d1 * d1 + d2 * d2 + d3 * d3;
    #pragma unroll
    for (int off = 32; off; off >>= 1) ss += __shfl_down(ss, off);
    if ((t & 63) == 0) sh[t >> 6] = ss;
    __syncthreads();
    float var = (sh[0] + sh[1] + sh[2] + sh[3]) * (1.0f / D_);
    float rs = rsqrtf(var + 1e-5f);

    float4 o;
    o.x = d0 * rs; o.y = d1 * rs; o.z = d2 * rs; o.w = d3 * rs;
    ((float4*)(O + row * D_))[t] = o;
}

extern "C" void kernel_launch(void* const* d_in, const int* in_sizes, int n_in,
                              void* d_out, int out_size, void* d_ws, size_t ws_size,
                              hipStream_t stream) {
    const float* q  = (const float*)d_in[0];
    const float* k  = (const float*)d_in[1];
    const float* v  = (const float*)d_in[2];
    const float* Wq = (const float*)d_in[3];
    const float* bq = (const float*)d_in[4];
    const float* Wk = (const float*)d_in[5];
    const float* bk = (const float*)d_in[6];
    const float* Wv = (const float*)d_in[7];
    const float* bv = (const float*)d_in[8];
    const float* Wo = (const float*)d_in[9];
    const float* bo = (const float*)d_in[10];
    float* out = (float*)d_out;

    char* ws = (char*)d_ws;
    const size_t SZ = (size_t)B_ * L_ * D_ * 2;  // 33,554,432 B (one [B,L,D] bf16)

    // Region A (4*SZ): qb,kb,vb,vpb -> then S(2*SZ) | P at +2*SZ -> then O(SZ) | X at +2*SZ
    u16* qb   = (u16*)(ws + 0 * SZ);
    u16* kb   = (u16*)(ws + 1 * SZ);
    u16* vb   = (u16*)(ws + 2 * SZ);
    u16* vpb  = (u16*)(ws + 3 * SZ);
    u16* Sbuf = (u16*)(ws + 0 * SZ);       // 2*SZ bytes, alive: scores GEMM -> softmax
    u16* Pbuf = (u16*)(ws + 2 * SZ);       // 2*SZ bytes, alive: softmax -> PV GEMM
    u16* Obuf = (u16*)(ws + 0 * SZ);       // SZ bytes,  alive: PV GEMM -> outproj
    u16* Xbuf = (u16*)(ws + 2 * SZ);       // SZ bytes,  alive: outproj -> layernorm
    char* p = ws + 4 * SZ;
    u16* qpb = (u16*)p; p += SZ;           // projected q (bf16), also residual
    u16* kpb = (u16*)p; p += SZ;
    u16* vpT = (u16*)p; p += SZ;           // transposed projected v
    u16* Wqb = (u16*)p; p += (size_t)D_ * D_ * 2;  // Wqb..Wob contiguous
    u16* Wkb = (u16*)p; p += (size_t)D_ * D_ * 2;
    u16* Wvb = (u16*)p; p += (size_t)D_ * D_ * 2;
    u16* Wob = (u16*)p; p += (size_t)D_ * D_ * 2;
    int* maskq = (int*)p; p += (size_t)B_ * L_ * 4;
    int* maskk = (int*)p; p += (size_t)B_ * L_ * 4;
    int* maskv = (int*)p; p += (size_t)B_ * L_ * 4;
    int* q256 = (int*)p; p += 64 * 4;        // [B*L/256]
    int* k256 = (int*)p; p += 64 * 4;
    int* v256 = (int*)p; p += 64 * 4;
    int* kmask128 = (int*)p; p += 128 * 4;   // [B][L/128]
    int* kmask32  = (int*)p; p += 512 * 4;   // [B][L/32]
    unsigned long long* kbits = (unsigned long long*)p; p += 8 * 8;  // [B] active-64-step bitmask

    P3 noP3 = {};

    // 1. fused conversions + masks (q,k,v in one dispatch), weights, flags, bitmask
    CM3 cm;
    cm.s[0] = q;  cm.s[1] = k;  cm.s[2] = v;
    cm.d[0] = qb; cm.d[1] = kb; cm.d[2] = vb;
    cm.m[0] = maskq; cm.m[1] = maskk; cm.m[2] = maskv;
    convmask3_kernel<<<dim3(B_ * L_, 3), 256, 0, stream>>>(cm);
    Ptr4 wp{Wq, Wk, Wv, Wo};
    convert4_kernel<<<dim3(D_ * D_ / 4 / 256, 4), 256, 0, stream>>>(wp, Wqb);
    flags_kernel<<<832, 256, 0, stream>>>(maskq, maskk, maskv, q256, k256, v256, kmask128, kmask32);
    packbits_kernel<<<1, 256, 0, stream>>>(kmask32, kbits);

    // 2. merged projections: 3 x [16384,1024] x [1024,1024]^T via grid.z
    P3 pj;
    pj.A[0] = qb;  pj.A[1] = kb;  pj.A[2] = vb;
    pj.C[0] = qpb; pj.C[1] = kpb; pj.C[2] = vpb;
    pj.bias[0] = bq; pj.bias[1] = bk; pj.bias[2] = bv;
    pj.rs[0] = q256; pj.rs[1] = k256; pj.rs[2] = v256;
    gemm_nt<0><<<dim3(B_ * L_ / GBM, D_ / GBN, 3), 512, 0, stream>>>(
        nullptr, Wqb, nullptr, nullptr, nullptr, nullptr, D_, D_, 0, 0, 0, 0.f,
        nullptr, nullptr, nullptr, 0, 4, pj);

    // 3. transpose vp for the PV GEMM
    transpose_k<<<dim3(D_ / 32, L_ / 32, B_), dim3(32, 8), 0, stream>>>(vpb, vpT);

    // 4. scores: S[b,i,j] = scale * qp_i . kp_j, key-masked; skip q-/k-masked blocks
    gemm_nt<1><<<dim3(L_ / GBM, L_ / GBN, B_), 512, 0, stream>>>(
        qpb, kpb, Sbuf, nullptr, nullptr, maskk, L_, D_,
        (long)L_ * D_, (long)L_ * D_, (long)L_ * L_ * 2, 0.03125f,
        q256, k256, nullptr, L_ / GBM, L_ / GBN, noP3);

    // 5. softmax rows (query-mask folded into P)
    softmax_kernel<<<B_ * L_, 256, 0, stream>>>(Sbuf, Pbuf, maskq);

    // 6. O = P @ vp (via vpT, NT); skip q-masked row blocks; 64-row k-steps gated by kbits
    gemm_nt<2><<<dim3(L_ / GBM, D_ / GBN, B_), 512, 0, stream>>>(
        Pbuf, vpT, Obuf, nullptr, nullptr, nullptr, D_, L_,
        (long)L_ * L_, (long)D_ * L_, (long)L_ * D_ * 2, 0.f,
        q256, nullptr, kbits, L_ / GBM, D_ / GBN, noP3);

    // 7. out-proj + bias + residual(qp) -> bf16; skip q-masked row blocks (acc=0 exact)
    gemm_nt<3><<<dim3(B_ * L_ / GBM, D_ / GBN, 1), 512, 0, stream>>>(
        Obuf, Wob, Xbuf, bo, qpb, nullptr, D_, D_, 0, 0, 0, 0.f,
        q256, nullptr, nullptr, B_ * L_ / GBM, D_ / GBN, noP3);

    // 8. LayerNorm (bf16 in, f32 out) -> d_out
    layernorm_kernel<<<B_ * L_, 256, 0, stream>>>(Xbuf, out);
}